// Round 3
// baseline (752.432 us; speedup 1.0000x reference)
//
#include <hip/hip_runtime.h>

#define D_FEAT 64
#define SCAN_BLOCK 256
#define SCAN_ITEMS 16
#define SCAN_CHUNK (SCAN_BLOCK * SCAN_ITEMS)   // 4096 elements per scan block
#define SCANB_THREADS 1024                     // supports up to 1024 scan blocks (~4.2M rows)

#define EMPTY_SLOT 0xFFFFFFFFu
#define ROW_CAP 16                              // 16 u32 slots = one 64B line per row

typedef unsigned int u32;
typedef float f4 __attribute__((ext_vector_type(4)));

// ===================== TIER 1: CAS-claim row buckets ================================
// slots[row*16 + k] holds col | sign<<31. Init to EMPTY (0xFFFFFFFF; impossible entry
// since col < 2^31). Each edge claims a slot via atomicCAS with linear probing inside
// the row's own 64B line: the CAS *is* the store (no cnt array, no dependent store).
// Rows with degree > 16 overflow into a small spill list applied atomically at the end.

__device__ __forceinline__ void slow_claim(u32* __restrict__ line, u32 entry, u32 h,
                                           u32 r, u32* __restrict__ spill,
                                           u32* __restrict__ spill_cnt, u32 spill_cap) {
    for (u32 p = 1; p < ROW_CAP; ++p) {
        u32 old = atomicCAS(line + ((h + p) & (ROW_CAP - 1)), EMPTY_SLOT, entry);
        if (old == EMPTY_SLOT) return;
    }
    u32 kk = atomicAdd(spill_cnt, 1u);
    if (kk < spill_cap) { spill[2 * kk] = r; spill[2 * kk + 1] = entry; }
}

__global__ __launch_bounds__(256) void scatter_cas_kernel(
    const int* __restrict__ rows, const int* __restrict__ cols,
    const float* __restrict__ vals, u32* __restrict__ slots,
    u32* __restrict__ spill, u32* __restrict__ spill_cnt, int nnz, u32 spill_cap) {
    long long i4 = (long long)blockIdx.x * blockDim.x + threadIdx.x;
    long long base = i4 * 4;
    if (base >= nnz) return;

    if (base + 3 < nnz) {
        int4 rr = *(const int4*)(rows + base);
        int4 cc = *(const int4*)(cols + base);
        float4 vv = *(const float4*)(vals + base);

        u32 e0 = (u32)cc.x | (vv.x < 0.f ? 0x80000000u : 0u);
        u32 e1 = (u32)cc.y | (vv.y < 0.f ? 0x80000000u : 0u);
        u32 e2 = (u32)cc.z | (vv.z < 0.f ? 0x80000000u : 0u);
        u32 e3 = (u32)cc.w | (vv.w < 0.f ? 0x80000000u : 0u);

        u32* L0 = slots + (size_t)rr.x * ROW_CAP;
        u32* L1 = slots + (size_t)rr.y * ROW_CAP;
        u32* L2 = slots + (size_t)rr.z * ROW_CAP;
        u32* L3 = slots + (size_t)rr.w * ROW_CAP;

        u32 h0 = (u32)(base + 0) & (ROW_CAP - 1);
        u32 h1 = (u32)(base + 1) & (ROW_CAP - 1);
        u32 h2 = (u32)(base + 2) & (ROW_CAP - 1);
        u32 h3 = (u32)(base + 3) & (ROW_CAP - 1);

        // 4 independent first-probe CAS in flight; slow path only on collision (~25%)
        u32 o0 = atomicCAS(L0 + h0, EMPTY_SLOT, e0);
        u32 o1 = atomicCAS(L1 + h1, EMPTY_SLOT, e1);
        u32 o2 = atomicCAS(L2 + h2, EMPTY_SLOT, e2);
        u32 o3 = atomicCAS(L3 + h3, EMPTY_SLOT, e3);

        if (o0 != EMPTY_SLOT) slow_claim(L0, e0, h0, (u32)rr.x, spill, spill_cnt, spill_cap);
        if (o1 != EMPTY_SLOT) slow_claim(L1, e1, h1, (u32)rr.y, spill, spill_cnt, spill_cap);
        if (o2 != EMPTY_SLOT) slow_claim(L2, e2, h2, (u32)rr.z, spill, spill_cnt, spill_cap);
        if (o3 != EMPTY_SLOT) slow_claim(L3, e3, h3, (u32)rr.w, spill, spill_cnt, spill_cap);
    } else {
        for (int k = 0; k < 4; ++k) {
            long long e = base + k;
            if (e >= nnz) break;
            int r = rows[e];
            u32 entry = (u32)cols[e] | (vals[e] < 0.f ? 0x80000000u : 0u);
            u32* line = slots + (size_t)r * ROW_CAP;
            u32 h = (u32)e & (ROW_CAP - 1);
            u32 old = atomicCAS(line + h, EMPTY_SLOT, entry);
            if (old != EMPTY_SLOT) slow_claim(line, entry, h, (u32)r, spill, spill_cnt, spill_cap);
        }
    }
}

// One wave = 4 rows, one 16-lane group per row. Each lane loads the row's whole 64B
// slot line via 4 uniform dwordx4 (L1 broadcast; replaces 16 ds_bpermute), then up to
// 16 predicated float4 feature loads in 2 batches of 8 (caps live VGPRs, >=8 loads in
// flight). Lane s owns dims [4s..4s+3]: no cross-lane reduce, no butterfly. Store is a
// coalesced 256B nontemporal line per group.
__global__ __launch_bounds__(256) void gather_cas_kernel(
    const f4* __restrict__ feat4, const u32* __restrict__ slots,
    f4* __restrict__ out4, int numV) {
    long long tid = (long long)blockIdx.x * blockDim.x + threadIdx.x;
    long long wid = tid >> 6;
    int lane = (int)(tid & 63);
    int g = lane >> 4;                  // group = row within wave
    int s = lane & 15;                  // f4 chunk of the feature row
    long long row = wid * 4 + g;
    if (row >= numV) return;

    const u32* line = slots + row * (long long)ROW_CAP;
    uint4 q0 = *(const uint4*)(line + 0);    // one 64B line, broadcast to the group
    uint4 q1 = *(const uint4*)(line + 4);
    uint4 q2 = *(const uint4*)(line + 8);
    uint4 q3 = *(const uint4*)(line + 12);

    const f4 z = {0.f, 0.f, 0.f, 0.f};
    f4 acc = z;

#define GATHER8(Ea, Eb, Ec, Ed, Ee, Ef, Eg2, Eh)                                   \
    {                                                                              \
        f4 fa = z, fb = z, fc = z, fd = z, fe = z, ff = z, fg = z, fh = z;         \
        if (Ea != EMPTY_SLOT) fa = feat4[(size_t)(Ea & 0x7fffffffu) * 16 + s];     \
        if (Eb != EMPTY_SLOT) fb = feat4[(size_t)(Eb & 0x7fffffffu) * 16 + s];     \
        if (Ec != EMPTY_SLOT) fc = feat4[(size_t)(Ec & 0x7fffffffu) * 16 + s];     \
        if (Ed != EMPTY_SLOT) fd = feat4[(size_t)(Ed & 0x7fffffffu) * 16 + s];     \
        if (Ee != EMPTY_SLOT) fe = feat4[(size_t)(Ee & 0x7fffffffu) * 16 + s];     \
        if (Ef != EMPTY_SLOT) ff = feat4[(size_t)(Ef & 0x7fffffffu) * 16 + s];     \
        if (Eg2 != EMPTY_SLOT) fg = feat4[(size_t)(Eg2 & 0x7fffffffu) * 16 + s];   \
        if (Eh != EMPTY_SLOT) fh = feat4[(size_t)(Eh & 0x7fffffffu) * 16 + s];     \
        acc += fa * ((Ea >> 31) ? -1.f : 1.f);                                     \
        acc += fb * ((Eb >> 31) ? -1.f : 1.f);                                     \
        acc += fc * ((Ec >> 31) ? -1.f : 1.f);                                     \
        acc += fd * ((Ed >> 31) ? -1.f : 1.f);                                     \
        acc += fe * ((Ee >> 31) ? -1.f : 1.f);                                     \
        acc += ff * ((Ef >> 31) ? -1.f : 1.f);                                     \
        acc += fg * ((Eg2 >> 31) ? -1.f : 1.f);                                    \
        acc += fh * ((Eh >> 31) ? -1.f : 1.f);                                     \
    }
    // EMPTY entries: f stays 0, sign -1 is harmless.
    GATHER8(q0.x, q0.y, q0.z, q0.w, q1.x, q1.y, q1.z, q1.w)
    GATHER8(q2.x, q2.y, q2.z, q2.w, q3.x, q3.y, q3.z, q3.w)
#undef GATHER8

    __builtin_nontemporal_store(acc, &out4[row * 16 + s]);
}

// Apply spilled edges (expected ~tens). One wave per entry, grid-stride.
__global__ __launch_bounds__(256) void spill_apply_kernel(
    const float* __restrict__ feat, const u32* __restrict__ spill,
    const u32* __restrict__ spill_cnt, float* __restrict__ out, u32 spill_cap) {
    u32 total = *spill_cnt;
    if (total > spill_cap) total = spill_cap;
    int lane = threadIdx.x & 63;
    u32 wid = (blockIdx.x * blockDim.x + threadIdx.x) >> 6;
    u32 nw = (gridDim.x * blockDim.x) >> 6;
    for (u32 i = wid; i < total; i += nw) {
        u32 r = spill[2 * i];
        u32 e = spill[2 * i + 1];
        float f = feat[(size_t)(e & 0x7fffffffu) * D_FEAT + lane];
        atomicAdd(&out[(size_t)r * D_FEAT + lane], (e & 0x80000000u) ? -f : f);
    }
}

// ===================== TIER 2: CSR build (count/scan/scatter) — verified path =======

__global__ __launch_bounds__(256) void count_kernel(const int* __restrict__ rows,
                                                    u32* __restrict__ cnt, int nnz) {
    int e = blockIdx.x * blockDim.x + threadIdx.x;
    if (e < nnz) atomicAdd(&cnt[rows[e]], 1u);
}

__global__ __launch_bounds__(SCAN_BLOCK) void scanA_kernel(const u32* __restrict__ cnt,
                                                           u32* __restrict__ bsums, int n) {
    int t = threadIdx.x, b = blockIdx.x;
    int i0 = b * SCAN_CHUNK + t * SCAN_ITEMS;
    u32 s = 0;
#pragma unroll
    for (int k = 0; k < SCAN_ITEMS; ++k) {
        int i = i0 + k;
        if (i < n) s += cnt[i];
    }
    __shared__ u32 red[SCAN_BLOCK];
    red[t] = s;
    __syncthreads();
    for (int d = SCAN_BLOCK / 2; d > 0; d >>= 1) {
        if (t < d) red[t] += red[t + d];
        __syncthreads();
    }
    if (t == 0) bsums[b] = red[0];
}

__global__ __launch_bounds__(SCANB_THREADS) void scanB_kernel(u32* __restrict__ bsums, int nb,
                                                              u32* __restrict__ off, int numV,
                                                              u32 nnz) {
    int t = threadIdx.x;
    __shared__ u32 tmp[SCANB_THREADS];
    u32 v = (t < nb) ? bsums[t] : 0u;
    tmp[t] = v;
    __syncthreads();
    for (int d = 1; d < SCANB_THREADS; d <<= 1) {
        u32 x = (t >= d) ? tmp[t - d] : 0u;
        __syncthreads();
        tmp[t] += x;
        __syncthreads();
    }
    if (t < nb) bsums[t] = tmp[t] - v;   // exclusive
    if (t == 0) off[numV] = nnz;
}

__global__ __launch_bounds__(SCAN_BLOCK) void scanC_kernel(const u32* __restrict__ cnt,
                                                           const u32* __restrict__ bsums,
                                                           u32* __restrict__ off,
                                                           u32* __restrict__ cursor, int n) {
    int t = threadIdx.x, b = blockIdx.x;
    int i0 = b * SCAN_CHUNK + t * SCAN_ITEMS;
    u32 s = 0;
#pragma unroll
    for (int k = 0; k < SCAN_ITEMS; ++k) {
        int i = i0 + k;
        if (i < n) s += cnt[i];
    }
    __shared__ u32 tmp[SCAN_BLOCK];
    tmp[t] = s;
    __syncthreads();
    for (int d = 1; d < SCAN_BLOCK; d <<= 1) {
        u32 x = (t >= d) ? tmp[t - d] : 0u;
        __syncthreads();
        tmp[t] += x;
        __syncthreads();
    }
    u32 run = bsums[b] + (tmp[t] - s);
    for (int k = 0; k < SCAN_ITEMS; ++k) {
        int i = i0 + k;
        if (i < n) {
            off[i] = run;
            cursor[i] = run;
            run += cnt[i];
        }
    }
}

__global__ __launch_bounds__(256) void scatter_kernel(const int* __restrict__ rows,
                                                      const int* __restrict__ cols,
                                                      const float* __restrict__ vals,
                                                      u32* __restrict__ cursor,
                                                      u32* __restrict__ packed, int nnz) {
    int e = blockIdx.x * blockDim.x + threadIdx.x;
    if (e >= nnz) return;
    int r = rows[e];
    u32 pos = atomicAdd(&cursor[r], 1u);
    u32 entry = (u32)cols[e] | (vals[e] < 0.f ? 0x80000000u : 0u);
    packed[pos] = entry;
}

__global__ __launch_bounds__(256) void gather_kernel(const float* __restrict__ feat,
                                                     const u32* __restrict__ off,
                                                     const u32* __restrict__ packed,
                                                     float* __restrict__ out, int numV) {
    long long tid = (long long)blockIdx.x * blockDim.x + threadIdx.x;
    long long wid = tid >> 6;
    int lane = (int)(tid & 63);
    if (wid >= numV) return;

    u32 s = off[wid];
    u32 e = off[wid + 1];
    float acc = 0.f;

    for (u32 base = s; base < e; base += 64) {
        int cnt = (int)min(64u, e - base);
        u32 ent = (lane < cnt) ? packed[base + lane] : 0u;
        for (int j0 = 0; j0 < cnt; j0 += 4) {
            float f[4], sg[4];
#pragma unroll
            for (int k = 0; k < 4; ++k) {
                int j = j0 + k;
                u32 ej = __shfl(ent, j);
                long long c = (long long)(ej & 0x7fffffffu);
                sg[k] = (ej >> 31) ? -1.f : 1.f;
                f[k] = (j < cnt) ? feat[c * D_FEAT + lane] : 0.f;
            }
#pragma unroll
            for (int k = 0; k < 4; ++k) acc = fmaf(sg[k], f[k], acc);
        }
    }
    out[wid * D_FEAT + lane] = acc;
}

// ===================== TIER 3: atomic fallback ======================================
__global__ __launch_bounds__(256) void atomic_fallback_kernel(
    const float* __restrict__ feat, const float* __restrict__ vals,
    const int* __restrict__ rows, const int* __restrict__ cols,
    float* __restrict__ out, long long nnz) {
    long long tid = (long long)blockIdx.x * blockDim.x + threadIdx.x;
    long long e = tid >> 6;
    int d = (int)(tid & 63);
    if (e >= nnz) return;
    float f = feat[(long long)cols[e] * D_FEAT + d];
    atomicAdd(out + (long long)rows[e] * D_FEAT + d, vals[e] * f);
}

extern "C" void kernel_launch(void* const* d_in, const int* in_sizes, int n_in,
                              void* d_out, int out_size, void* d_ws, size_t ws_size,
                              hipStream_t stream) {
    const float* feat = (const float*)d_in[0];  // [NUM_E, 64] fp32
    const float* vals = (const float*)d_in[1];  // [NNZ] fp32 (+/-1)
    const int*   rows = (const int*)d_in[2];    // [NNZ] int32
    const int*   cols = (const int*)d_in[3];    // [NNZ] int32
    float*       out  = (float*)d_out;          // [NUM_V, 64] fp32

    int nnz  = in_sizes[1];
    int numV = out_size / D_FEAT;

    // ---------------- TIER 1: CAS-claim slot buckets --------------------------------
    {
        // ws layout (u32): [spill_cnt + pad: 16][slots: numV*16][spill: 2*spcap]
        const u32 spcap = 1u << 20;
        size_t needT1 = (16 + (size_t)numV * ROW_CAP + 2 * (size_t)spcap) * sizeof(u32);
        if (ws_size >= needT1) {
            u32* ws        = (u32*)d_ws;
            u32* spill_cnt = ws;
            u32* slots     = ws + 16;
            u32* spill     = slots + (size_t)numV * ROW_CAP;

            hipMemsetAsync(spill_cnt, 0, 16 * sizeof(u32), stream);
            hipMemsetAsync(slots, 0xFF, (size_t)numV * ROW_CAP * sizeof(u32), stream);

            long long nth4 = ((long long)nnz + 3) / 4;
            int nb4 = (int)((nth4 + 255) / 256);
            scatter_cas_kernel<<<nb4, 256, 0, stream>>>(rows, cols, vals, slots,
                                                        spill, spill_cnt, nnz, spcap);

            long long waves = ((long long)numV + 3) / 4;
            long long gthreads = waves * 64;
            int gblocks = (int)((gthreads + 255) / 256);
            gather_cas_kernel<<<gblocks, 256, 0, stream>>>((const f4*)feat, slots,
                                                           (f4*)out, numV);
            spill_apply_kernel<<<64, 256, 0, stream>>>(feat, spill, spill_cnt, out, spcap);
            return;
        }
    }

    // ---------------- TIER 2: CSR build (previous verified path) --------------------
    int nScanBlocks = (numV + SCAN_CHUNK - 1) / SCAN_CHUNK;
    size_t need = ((size_t)(numV + 1) + numV + numV + SCANB_THREADS + nnz) * sizeof(u32);

    if (ws_size < need || nScanBlocks > SCANB_THREADS) {
        hipMemsetAsync(d_out, 0, (size_t)out_size * sizeof(float), stream);
        long long total = (long long)nnz * D_FEAT;
        long long nblk = (total + 255) / 256;
        atomic_fallback_kernel<<<(dim3)((unsigned)nblk), 256, 0, stream>>>(
            feat, vals, rows, cols, out, nnz);
        return;
    }

    u32* ws     = (u32*)d_ws;
    u32* off    = ws;
    u32* cursor = off + (numV + 1);
    u32* cnt    = cursor + numV;
    u32* bsums  = cnt + numV;
    u32* packed = bsums + SCANB_THREADS;

    hipMemsetAsync(cnt, 0, (size_t)numV * sizeof(u32), stream);

    int nb256 = (nnz + 255) / 256;
    count_kernel<<<nb256, 256, 0, stream>>>(rows, cnt, nnz);
    scanA_kernel<<<nScanBlocks, SCAN_BLOCK, 0, stream>>>(cnt, bsums, numV);
    scanB_kernel<<<1, SCANB_THREADS, 0, stream>>>(bsums, nScanBlocks, off, numV, (u32)nnz);
    scanC_kernel<<<nScanBlocks, SCAN_BLOCK, 0, stream>>>(cnt, bsums, off, cursor, numV);
    scatter_kernel<<<nb256, 256, 0, stream>>>(rows, cols, vals, cursor, packed, nnz);

    long long gthreads = (long long)numV * 64;
    long long gblocks  = (gthreads + 255) / 256;
    gather_kernel<<<(dim3)((unsigned)gblocks), 256, 0, stream>>>(feat, off, packed, out, numV);
}

// Round 4
// 662.800 us; speedup vs baseline: 1.1352x; 1.1352x over previous
//
#include <hip/hip_runtime.h>

#define D_FEAT 64
#define SCAN_BLOCK 256
#define SCAN_ITEMS 16
#define SCAN_CHUNK (SCAN_BLOCK * SCAN_ITEMS)
#define SCANB_THREADS 1024

#define EMPTY_SLOT 0xFFFFFFFFu
#define ROW_CAP 16                              // 16 u32 slots = one 64B line per row

// ---- radix tier params ----
#define RADIX_SHIFT 10                          // rows per bucket = 1024
#define ROWS_PER_BUCKET 1024
#define HALF_ROWS 512
#define RADIX_NB_MAX 512
#define EPB 4096                                // edges per pass-1 block
#define CURSOR_STRIDE 16                        // pad cursors to 64B lines

typedef unsigned int u32;
typedef unsigned long long u64;
typedef float f4 __attribute__((ext_vector_type(4)));

// ===================== TIER 1a: atomic-free two-pass LDS multisplit =================
// Pass 1: bin edges by row>>10 into <=512 bucket regions. Ranks via LDS atomics;
// one global atomicAdd per (block,bucket) reserves space (~10x fewer global atomics).
// Pass 2: per (bucket, half), build 512 rows x 16 slot lines in LDS, dump coalesced.

__global__ __launch_bounds__(256) void radix_bin_kernel(
    const int* __restrict__ rows, const int* __restrict__ cols,
    const float* __restrict__ vals, u32* __restrict__ cursor,
    u64* __restrict__ binned, u32* __restrict__ spill, u32* __restrict__ spill_cnt,
    int nnz, int NB, u32 CAP, u32 spill_cap) {
    __shared__ u32 hist[RADIX_NB_MAX];
    __shared__ u32 sbase[RADIX_NB_MAX];
    int t = threadIdx.x;
    long long b0 = (long long)blockIdx.x * EPB;

    for (int i = t; i < RADIX_NB_MAX; i += 256) hist[i] = 0;
    __syncthreads();

    // 16 edges per thread: i = b0 + t*4 + k*1024 + j  (int4-coalesced groups)
    u32 pack[16];      // digit(9b) | rank<<9 (12b) | valid<<31
    u64 ent[16];       // rowlo<<32 | col|sign
#pragma unroll
    for (int k = 0; k < 4; ++k) {
        long long i = b0 + (long long)t * 4 + (long long)k * 1024;
        int4 rr = {0, 0, 0, 0}, cc = {0, 0, 0, 0};
        float4 vv = {0.f, 0.f, 0.f, 0.f};
        bool v4 = (i + 3 < nnz);
        if (v4) {
            rr = *(const int4*)(rows + i);
            cc = *(const int4*)(cols + i);
            vv = *(const float4*)(vals + i);
        }
#define DO_EDGE(J, RJ, CJ, VJ)                                                      \
        {                                                                           \
            long long e = i + J;                                                    \
            int r = RJ, c = CJ; float v = VJ;                                       \
            bool valid = v4;                                                        \
            if (!v4) {                                                              \
                valid = (e < nnz);                                                  \
                if (valid) { r = rows[e]; c = cols[e]; v = vals[e]; }               \
                else { r = 0; c = 0; v = 0.f; }                                     \
            }                                                                       \
            u32 digit = (u32)r >> RADIX_SHIFT;                                      \
            u32 rank = 0;                                                           \
            if (valid) rank = atomicAdd(&hist[digit], 1u);                          \
            pack[k * 4 + J] = digit | (rank << 9) | (valid ? 0x80000000u : 0u);     \
            ent[k * 4 + J] = ((u64)((u32)r & (ROWS_PER_BUCKET - 1)) << 32) |        \
                             (u64)((u32)c | (v < 0.f ? 0x80000000u : 0u));          \
        }
        DO_EDGE(0, rr.x, cc.x, vv.x)
        DO_EDGE(1, rr.y, cc.y, vv.y)
        DO_EDGE(2, rr.z, cc.z, vv.z)
        DO_EDGE(3, rr.w, cc.w, vv.w)
#undef DO_EDGE
    }
    __syncthreads();

    for (int i = t; i < RADIX_NB_MAX; i += 256) {
        u32 c = hist[i];
        sbase[i] = c ? atomicAdd(&cursor[i * CURSOR_STRIDE], c) : 0u;
    }
    __syncthreads();

#pragma unroll
    for (int q = 0; q < 16; ++q) {
        u32 p = pack[q];
        if (p & 0x80000000u) {
            u32 digit = p & 0x1FFu;
            u32 pos = sbase[digit] + ((p >> 9) & 0xFFFu);
            if (pos < CAP) {
                binned[(size_t)digit * CAP + pos] = ent[q];
            } else {
                u32 kk = atomicAdd(spill_cnt, 1u);
                u32 r = (digit << RADIX_SHIFT) | (u32)(ent[q] >> 32);
                if (kk < spill_cap) { spill[2 * kk] = r; spill[2 * kk + 1] = (u32)ent[q]; }
            }
        }
    }
}

__global__ __launch_bounds__(256) void radix_place_kernel(
    const u64* __restrict__ binned, const u32* __restrict__ cursor,
    u32* __restrict__ slots, u32* __restrict__ spill, u32* __restrict__ spill_cnt,
    u32 CAP, u32 spill_cap) {
    __shared__ u32 table[HALF_ROWS * ROW_CAP];   // 32 KB
    __shared__ u32 rcnt[HALF_ROWS];              // 2 KB
    int t = threadIdx.x;
    int b = blockIdx.x >> 1;       // bucket
    int h = blockIdx.x & 1;        // which 512-row half

    for (int i = t; i < HALF_ROWS * ROW_CAP; i += 256) table[i] = EMPTY_SLOT;
    for (int i = t; i < HALF_ROWS; i += 256) rcnt[i] = 0;
    __syncthreads();

    u32 count = cursor[b * CURSOR_STRIDE];
    if (count > CAP) count = CAP;
    const u64* src = binned + (size_t)b * CAP;
    for (u32 i = t; i < count; i += 256) {
        u64 e = src[i];
        u32 rowlo = (u32)(e >> 32);              // 0..1023
        if ((int)(rowlo >> 9) == h) {
            u32 rl = rowlo & (HALF_ROWS - 1);
            u32 k = atomicAdd(&rcnt[rl], 1u);
            if (k < ROW_CAP) {
                table[rl * ROW_CAP + k] = (u32)e;
            } else {
                u32 kk = atomicAdd(spill_cnt, 1u);
                u32 r = ((u32)b << RADIX_SHIFT) | rowlo;
                if (kk < spill_cap) { spill[2 * kk] = r; spill[2 * kk + 1] = (u32)e; }
            }
        }
    }
    __syncthreads();

    // coalesced 32 KB dump: rows [b*1024 + h*512, +512) -> slots
    u32 rowbase = ((u32)b << RADIX_SHIFT) | ((u32)h << 9);
    uint4* dst = (uint4*)(slots + (size_t)rowbase * ROW_CAP);
    const uint4* srcT = (const uint4*)table;
    for (int i = t; i < HALF_ROWS * ROW_CAP / 4; i += 256) dst[i] = srcT[i];
}

// ===================== TIER 1b: CAS-claim row buckets (fallback, verified) ==========

__device__ __forceinline__ void slow_claim(u32* __restrict__ line, u32 entry, u32 h,
                                           u32 r, u32* __restrict__ spill,
                                           u32* __restrict__ spill_cnt, u32 spill_cap) {
    for (u32 p = 1; p < ROW_CAP; ++p) {
        u32 old = atomicCAS(line + ((h + p) & (ROW_CAP - 1)), EMPTY_SLOT, entry);
        if (old == EMPTY_SLOT) return;
    }
    u32 kk = atomicAdd(spill_cnt, 1u);
    if (kk < spill_cap) { spill[2 * kk] = r; spill[2 * kk + 1] = entry; }
}

__global__ __launch_bounds__(256) void scatter_cas_kernel(
    const int* __restrict__ rows, const int* __restrict__ cols,
    const float* __restrict__ vals, u32* __restrict__ slots,
    u32* __restrict__ spill, u32* __restrict__ spill_cnt, int nnz, u32 spill_cap) {
    long long i4 = (long long)blockIdx.x * blockDim.x + threadIdx.x;
    long long base = i4 * 4;
    if (base >= nnz) return;

    if (base + 3 < nnz) {
        int4 rr = *(const int4*)(rows + base);
        int4 cc = *(const int4*)(cols + base);
        float4 vv = *(const float4*)(vals + base);

        u32 e0 = (u32)cc.x | (vv.x < 0.f ? 0x80000000u : 0u);
        u32 e1 = (u32)cc.y | (vv.y < 0.f ? 0x80000000u : 0u);
        u32 e2 = (u32)cc.z | (vv.z < 0.f ? 0x80000000u : 0u);
        u32 e3 = (u32)cc.w | (vv.w < 0.f ? 0x80000000u : 0u);

        u32* L0 = slots + (size_t)rr.x * ROW_CAP;
        u32* L1 = slots + (size_t)rr.y * ROW_CAP;
        u32* L2 = slots + (size_t)rr.z * ROW_CAP;
        u32* L3 = slots + (size_t)rr.w * ROW_CAP;

        u32 h0 = (u32)(base + 0) & (ROW_CAP - 1);
        u32 h1 = (u32)(base + 1) & (ROW_CAP - 1);
        u32 h2 = (u32)(base + 2) & (ROW_CAP - 1);
        u32 h3 = (u32)(base + 3) & (ROW_CAP - 1);

        u32 o0 = atomicCAS(L0 + h0, EMPTY_SLOT, e0);
        u32 o1 = atomicCAS(L1 + h1, EMPTY_SLOT, e1);
        u32 o2 = atomicCAS(L2 + h2, EMPTY_SLOT, e2);
        u32 o3 = atomicCAS(L3 + h3, EMPTY_SLOT, e3);

        if (o0 != EMPTY_SLOT) slow_claim(L0, e0, h0, (u32)rr.x, spill, spill_cnt, spill_cap);
        if (o1 != EMPTY_SLOT) slow_claim(L1, e1, h1, (u32)rr.y, spill, spill_cnt, spill_cap);
        if (o2 != EMPTY_SLOT) slow_claim(L2, e2, h2, (u32)rr.z, spill, spill_cnt, spill_cap);
        if (o3 != EMPTY_SLOT) slow_claim(L3, e3, h3, (u32)rr.w, spill, spill_cnt, spill_cap);
    } else {
        for (int k = 0; k < 4; ++k) {
            long long e = base + k;
            if (e >= nnz) break;
            int r = rows[e];
            u32 entry = (u32)cols[e] | (vals[e] < 0.f ? 0x80000000u : 0u);
            u32* line = slots + (size_t)r * ROW_CAP;
            u32 h = (u32)e & (ROW_CAP - 1);
            u32 old = atomicCAS(line + h, EMPTY_SLOT, entry);
            if (old != EMPTY_SLOT) slow_claim(line, entry, h, (u32)r, spill, spill_cnt, spill_cap);
        }
    }
}

// ===================== Gather (shared by tiers 1a/1b) ===============================
// One wave = 4 rows, one 16-lane group per row; lane s owns dims [4s..4s+3].
__global__ __launch_bounds__(256) void gather_cas_kernel(
    const f4* __restrict__ feat4, const u32* __restrict__ slots,
    f4* __restrict__ out4, int numV) {
    long long tid = (long long)blockIdx.x * blockDim.x + threadIdx.x;
    long long wid = tid >> 6;
    int lane = (int)(tid & 63);
    int g = lane >> 4;
    int s = lane & 15;
    long long row = wid * 4 + g;
    if (row >= numV) return;

    const u32* line = slots + row * (long long)ROW_CAP;
    uint4 q0 = *(const uint4*)(line + 0);
    uint4 q1 = *(const uint4*)(line + 4);
    uint4 q2 = *(const uint4*)(line + 8);
    uint4 q3 = *(const uint4*)(line + 12);

    const f4 z = {0.f, 0.f, 0.f, 0.f};
    f4 acc = z;

#define GATHER8(Ea, Eb, Ec, Ed, Ee, Ef, Eg2, Eh)                                   \
    {                                                                              \
        f4 fa = z, fb = z, fc = z, fd = z, fe = z, ff = z, fg = z, fh = z;         \
        if (Ea != EMPTY_SLOT) fa = feat4[(size_t)(Ea & 0x7fffffffu) * 16 + s];     \
        if (Eb != EMPTY_SLOT) fb = feat4[(size_t)(Eb & 0x7fffffffu) * 16 + s];     \
        if (Ec != EMPTY_SLOT) fc = feat4[(size_t)(Ec & 0x7fffffffu) * 16 + s];     \
        if (Ed != EMPTY_SLOT) fd = feat4[(size_t)(Ed & 0x7fffffffu) * 16 + s];     \
        if (Ee != EMPTY_SLOT) fe = feat4[(size_t)(Ee & 0x7fffffffu) * 16 + s];     \
        if (Ef != EMPTY_SLOT) ff = feat4[(size_t)(Ef & 0x7fffffffu) * 16 + s];     \
        if (Eg2 != EMPTY_SLOT) fg = feat4[(size_t)(Eg2 & 0x7fffffffu) * 16 + s];   \
        if (Eh != EMPTY_SLOT) fh = feat4[(size_t)(Eh & 0x7fffffffu) * 16 + s];     \
        acc += fa * ((Ea >> 31) ? -1.f : 1.f);                                     \
        acc += fb * ((Eb >> 31) ? -1.f : 1.f);                                     \
        acc += fc * ((Ec >> 31) ? -1.f : 1.f);                                     \
        acc += fd * ((Ed >> 31) ? -1.f : 1.f);                                     \
        acc += fe * ((Ee >> 31) ? -1.f : 1.f);                                     \
        acc += ff * ((Ef >> 31) ? -1.f : 1.f);                                     \
        acc += fg * ((Eg2 >> 31) ? -1.f : 1.f);                                    \
        acc += fh * ((Eh >> 31) ? -1.f : 1.f);                                     \
    }
    GATHER8(q0.x, q0.y, q0.z, q0.w, q1.x, q1.y, q1.z, q1.w)
    GATHER8(q2.x, q2.y, q2.z, q2.w, q3.x, q3.y, q3.z, q3.w)
#undef GATHER8

    __builtin_nontemporal_store(acc, &out4[row * 16 + s]);
}

__global__ __launch_bounds__(256) void spill_apply_kernel(
    const float* __restrict__ feat, const u32* __restrict__ spill,
    const u32* __restrict__ spill_cnt, float* __restrict__ out, u32 spill_cap) {
    u32 total = *spill_cnt;
    if (total > spill_cap) total = spill_cap;
    int lane = threadIdx.x & 63;
    u32 wid = (blockIdx.x * blockDim.x + threadIdx.x) >> 6;
    u32 nw = (gridDim.x * blockDim.x) >> 6;
    for (u32 i = wid; i < total; i += nw) {
        u32 r = spill[2 * i];
        u32 e = spill[2 * i + 1];
        float f = feat[(size_t)(e & 0x7fffffffu) * D_FEAT + lane];
        atomicAdd(&out[(size_t)r * D_FEAT + lane], (e & 0x80000000u) ? -f : f);
    }
}

// ===================== TIER 2: CSR build — verified path ============================

__global__ __launch_bounds__(256) void count_kernel(const int* __restrict__ rows,
                                                    u32* __restrict__ cnt, int nnz) {
    int e = blockIdx.x * blockDim.x + threadIdx.x;
    if (e < nnz) atomicAdd(&cnt[rows[e]], 1u);
}

__global__ __launch_bounds__(SCAN_BLOCK) void scanA_kernel(const u32* __restrict__ cnt,
                                                           u32* __restrict__ bsums, int n) {
    int t = threadIdx.x, b = blockIdx.x;
    int i0 = b * SCAN_CHUNK + t * SCAN_ITEMS;
    u32 s = 0;
#pragma unroll
    for (int k = 0; k < SCAN_ITEMS; ++k) {
        int i = i0 + k;
        if (i < n) s += cnt[i];
    }
    __shared__ u32 red[SCAN_BLOCK];
    red[t] = s;
    __syncthreads();
    for (int d = SCAN_BLOCK / 2; d > 0; d >>= 1) {
        if (t < d) red[t] += red[t + d];
        __syncthreads();
    }
    if (t == 0) bsums[b] = red[0];
}

__global__ __launch_bounds__(SCANB_THREADS) void scanB_kernel(u32* __restrict__ bsums, int nb,
                                                              u32* __restrict__ off, int numV,
                                                              u32 nnz) {
    int t = threadIdx.x;
    __shared__ u32 tmp[SCANB_THREADS];
    u32 v = (t < nb) ? bsums[t] : 0u;
    tmp[t] = v;
    __syncthreads();
    for (int d = 1; d < SCANB_THREADS; d <<= 1) {
        u32 x = (t >= d) ? tmp[t - d] : 0u;
        __syncthreads();
        tmp[t] += x;
        __syncthreads();
    }
    if (t < nb) bsums[t] = tmp[t] - v;
    if (t == 0) off[numV] = nnz;
}

__global__ __launch_bounds__(SCAN_BLOCK) void scanC_kernel(const u32* __restrict__ cnt,
                                                           const u32* __restrict__ bsums,
                                                           u32* __restrict__ off,
                                                           u32* __restrict__ cursor, int n) {
    int t = threadIdx.x, b = blockIdx.x;
    int i0 = b * SCAN_CHUNK + t * SCAN_ITEMS;
    u32 s = 0;
#pragma unroll
    for (int k = 0; k < SCAN_ITEMS; ++k) {
        int i = i0 + k;
        if (i < n) s += cnt[i];
    }
    __shared__ u32 tmp[SCAN_BLOCK];
    tmp[t] = s;
    __syncthreads();
    for (int d = 1; d < SCAN_BLOCK; d <<= 1) {
        u32 x = (t >= d) ? tmp[t - d] : 0u;
        __syncthreads();
        tmp[t] += x;
        __syncthreads();
    }
    u32 run = bsums[b] + (tmp[t] - s);
    for (int k = 0; k < SCAN_ITEMS; ++k) {
        int i = i0 + k;
        if (i < n) {
            off[i] = run;
            cursor[i] = run;
            run += cnt[i];
        }
    }
}

__global__ __launch_bounds__(256) void scatter_kernel(const int* __restrict__ rows,
                                                      const int* __restrict__ cols,
                                                      const float* __restrict__ vals,
                                                      u32* __restrict__ cursor,
                                                      u32* __restrict__ packed, int nnz) {
    int e = blockIdx.x * blockDim.x + threadIdx.x;
    if (e >= nnz) return;
    int r = rows[e];
    u32 pos = atomicAdd(&cursor[r], 1u);
    u32 entry = (u32)cols[e] | (vals[e] < 0.f ? 0x80000000u : 0u);
    packed[pos] = entry;
}

__global__ __launch_bounds__(256) void gather_kernel(const float* __restrict__ feat,
                                                     const u32* __restrict__ off,
                                                     const u32* __restrict__ packed,
                                                     float* __restrict__ out, int numV) {
    long long tid = (long long)blockIdx.x * blockDim.x + threadIdx.x;
    long long wid = tid >> 6;
    int lane = (int)(tid & 63);
    if (wid >= numV) return;

    u32 s = off[wid];
    u32 e = off[wid + 1];
    float acc = 0.f;

    for (u32 base = s; base < e; base += 64) {
        int cnt = (int)min(64u, e - base);
        u32 ent = (lane < cnt) ? packed[base + lane] : 0u;
        for (int j0 = 0; j0 < cnt; j0 += 4) {
            float f[4], sg[4];
#pragma unroll
            for (int k = 0; k < 4; ++k) {
                int j = j0 + k;
                u32 ej = __shfl(ent, j);
                long long c = (long long)(ej & 0x7fffffffu);
                sg[k] = (ej >> 31) ? -1.f : 1.f;
                f[k] = (j < cnt) ? feat[c * D_FEAT + lane] : 0.f;
            }
#pragma unroll
            for (int k = 0; k < 4; ++k) acc = fmaf(sg[k], f[k], acc);
        }
    }
    out[wid * D_FEAT + lane] = acc;
}

// ===================== TIER 3: atomic fallback ======================================
__global__ __launch_bounds__(256) void atomic_fallback_kernel(
    const float* __restrict__ feat, const float* __restrict__ vals,
    const int* __restrict__ rows, const int* __restrict__ cols,
    float* __restrict__ out, long long nnz) {
    long long tid = (long long)blockIdx.x * blockDim.x + threadIdx.x;
    long long e = tid >> 6;
    int d = (int)(tid & 63);
    if (e >= nnz) return;
    float f = feat[(long long)cols[e] * D_FEAT + d];
    atomicAdd(out + (long long)rows[e] * D_FEAT + d, vals[e] * f);
}

extern "C" void kernel_launch(void* const* d_in, const int* in_sizes, int n_in,
                              void* d_out, int out_size, void* d_ws, size_t ws_size,
                              hipStream_t stream) {
    const float* feat = (const float*)d_in[0];  // [NUM_E, 64] fp32
    const float* vals = (const float*)d_in[1];  // [NNZ] fp32 (+/-1)
    const int*   rows = (const int*)d_in[2];    // [NNZ] int32
    const int*   cols = (const int*)d_in[3];    // [NNZ] int32
    float*       out  = (float*)d_out;          // [NUM_V, 64] fp32

    int nnz  = in_sizes[1];
    int numV = out_size / D_FEAT;

    // ---------------- TIER 1a: atomic-free radix build ------------------------------
    {
        int NB = (numV + ROWS_PER_BUCKET - 1) >> RADIX_SHIFT;
        const u32 spcap = 1u << 20;
        if (NB >= 1 && NB <= RADIX_NB_MAX && nnz >= 0) {
            u32 CAP = ((u32)(nnz / NB) * 2u + 1024u + 63u) & ~63u;
            size_t rowsPad = (size_t)NB << RADIX_SHIFT;      // slots rows allocated
            // ws layout (u32): [spill_cnt+pad: 16][cursor: 512*16][slots: rowsPad*16]
            //                  [binned: NB*CAP u64][spill: 2*spcap]
            size_t metaU   = 16 + (size_t)RADIX_NB_MAX * CURSOR_STRIDE;
            size_t slotsU  = rowsPad * ROW_CAP;
            size_t binnedU = (size_t)NB * CAP * 2;           // u64 in u32 units
            size_t need = (metaU + slotsU + binnedU + 2 * (size_t)spcap) * sizeof(u32);
            if (ws_size >= need) {
                u32* ws        = (u32*)d_ws;
                u32* spill_cnt = ws;
                u32* cursor    = ws + 16;
                u32* slots     = ws + metaU;
                u64* binned    = (u64*)(slots + slotsU);
                u32* spill     = (u32*)(binned + (size_t)NB * CAP);

                hipMemsetAsync(ws, 0, metaU * sizeof(u32), stream);

                if (nnz > 0) {
                    int nb1 = (int)(((long long)nnz + EPB - 1) / EPB);
                    radix_bin_kernel<<<nb1, 256, 0, stream>>>(
                        rows, cols, vals, cursor, binned, spill, spill_cnt,
                        nnz, NB, CAP, spcap);
                }
                radix_place_kernel<<<NB * 2, 256, 0, stream>>>(
                    binned, cursor, slots, spill, spill_cnt, CAP, spcap);

                long long waves = ((long long)numV + 3) / 4;
                long long gthreads = waves * 64;
                int gblocks = (int)((gthreads + 255) / 256);
                gather_cas_kernel<<<gblocks, 256, 0, stream>>>((const f4*)feat, slots,
                                                               (f4*)out, numV);
                spill_apply_kernel<<<64, 256, 0, stream>>>(feat, spill, spill_cnt, out, spcap);
                return;
            }
        }
    }

    // ---------------- TIER 1b: CAS-claim slot buckets (verified) --------------------
    {
        const u32 spcap = 1u << 20;
        size_t needT1 = (16 + (size_t)numV * ROW_CAP + 2 * (size_t)spcap) * sizeof(u32);
        if (ws_size >= needT1) {
            u32* ws        = (u32*)d_ws;
            u32* spill_cnt = ws;
            u32* slots     = ws + 16;
            u32* spill     = slots + (size_t)numV * ROW_CAP;

            hipMemsetAsync(spill_cnt, 0, 16 * sizeof(u32), stream);
            hipMemsetAsync(slots, 0xFF, (size_t)numV * ROW_CAP * sizeof(u32), stream);

            long long nth4 = ((long long)nnz + 3) / 4;
            int nb4 = (int)((nth4 + 255) / 256);
            scatter_cas_kernel<<<nb4, 256, 0, stream>>>(rows, cols, vals, slots,
                                                        spill, spill_cnt, nnz, spcap);

            long long waves = ((long long)numV + 3) / 4;
            long long gthreads = waves * 64;
            int gblocks = (int)((gthreads + 255) / 256);
            gather_cas_kernel<<<gblocks, 256, 0, stream>>>((const f4*)feat, slots,
                                                           (f4*)out, numV);
            spill_apply_kernel<<<64, 256, 0, stream>>>(feat, spill, spill_cnt, out, spcap);
            return;
        }
    }

    // ---------------- TIER 2: CSR build ----------------------------------------------
    int nScanBlocks = (numV + SCAN_CHUNK - 1) / SCAN_CHUNK;
    size_t need = ((size_t)(numV + 1) + numV + numV + SCANB_THREADS + nnz) * sizeof(u32);

    if (ws_size < need || nScanBlocks > SCANB_THREADS) {
        hipMemsetAsync(d_out, 0, (size_t)out_size * sizeof(float), stream);
        long long total = (long long)nnz * D_FEAT;
        long long nblk = (total + 255) / 256;
        atomic_fallback_kernel<<<(dim3)((unsigned)nblk), 256, 0, stream>>>(
            feat, vals, rows, cols, out, nnz);
        return;
    }

    u32* ws     = (u32*)d_ws;
    u32* off    = ws;
    u32* cursor = off + (numV + 1);
    u32* cnt    = cursor + numV;
    u32* bsums  = cnt + numV;
    u32* packed = bsums + SCANB_THREADS;

    hipMemsetAsync(cnt, 0, (size_t)numV * sizeof(u32), stream);

    int nb256 = (nnz + 255) / 256;
    count_kernel<<<nb256, 256, 0, stream>>>(rows, cnt, nnz);
    scanA_kernel<<<nScanBlocks, SCAN_BLOCK, 0, stream>>>(cnt, bsums, numV);
    scanB_kernel<<<1, SCANB_THREADS, 0, stream>>>(bsums, nScanBlocks, off, numV, (u32)nnz);
    scanC_kernel<<<nScanBlocks, SCAN_BLOCK, 0, stream>>>(cnt, bsums, off, cursor, numV);
    scatter_kernel<<<nb256, 256, 0, stream>>>(rows, cols, vals, cursor, packed, nnz);

    long long gthreads = (long long)numV * 64;
    long long gblocks  = (gthreads + 255) / 256;
    gather_kernel<<<(dim3)((unsigned)gblocks), 256, 0, stream>>>(feat, off, packed, out, numV);
}